// Round 9
// baseline (132.709 us; speedup 1.0000x reference)
//
#include <hip/hip_runtime.h>

// DecoderLayer: out[k,n,m] = tanh(sum_p w[k,p]*prev[idx[k,p],n,m] + b[k]),
// gated by (#active parents >= 12).  M=2048, K=4096, NN=4096 (64x64), P=16.
//
// R8: LDS gather, minimal instr count + conflict-free pattern.
//   - Measured law (R3/R5 vs R6): lane-INDEPENDENT random 16B LDS chunks run
//     at ~full b128 throughput (~0-1 conflicts/instr); lane-groups sharing a
//     row cost ~33 extra cyc/instr. So: thread owns ALL 16 positions of one
//     node; per parent row it issues 4 chunk b128s from ONE base addr
//     (+imm 0/16/32/48). Wave = 64 independent random rows per instr.
//   - Rows padded to 72B (18 words): start bank cycles through 16 positions
//     -> uniform bank spread with ZERO swizzle VALU and no acc permutation.
//     LDS = 2048*72 = 144 KiB (1 block/CU, 8 waves).
//   - sched_barrier(0) between 16-load cluster and FMA cluster forces the
//     compiler to keep 16 b128 in flight (R5/R7 collapsed to ~2, VGPR=36).

#define M_ROWS   2048
#define K_NODES  4096
#define NN       4096
#define POS_TILE 16
#define NTHREADS 512
#define ROW_W    18                         // words per padded row (72B)
#define LDS_BYTES (M_ROWS * ROW_W * 4)      // 147456 B
#define OUT_ELEMS (K_NODES * NN)
#define ACTIVE_THRESHOLD 12

typedef float f32x4 __attribute__((ext_vector_type(4)));

__device__ __forceinline__ float fast_tanh(float x) {
  float ax = __builtin_fabsf(x);
  float e  = __expf(-2.0f * ax);
  float r  = (1.0f - e) * __builtin_amdgcn_rcpf(1.0f + e);
  return __builtin_copysignf(r, x);
}

// Gate precompute (off hot path). Runtime-detects isact marshaling:
// any 32-bit word >1 in the first 2048 bytes implies packed bytes.
__global__ __launch_bounds__(256) void act_kernel(
    const int* __restrict__ pidx, const unsigned int* __restrict__ isact,
    float* __restrict__ outact) {
  __shared__ int mode_sh;
  if (threadIdx.x == 0) mode_sh = 0;
  __syncthreads();
  int bad = 0;
  for (int i = threadIdx.x; i < 512; i += 256) bad |= (isact[i] > 1u);
  if (bad) atomicOr(&mode_sh, 1);
  __syncthreads();
  const int shift = mode_sh ? 0 : 2;   // LSB byte of a 0/1 int32 == its value
  const unsigned char* actb = (const unsigned char*)isact;

  int k = blockIdx.x * 256 + threadIdx.x;
  const int4* ip = (const int4*)(pidx + k * 16);
  int4 ia = ip[0], ib = ip[1], ic = ip[2], id4 = ip[3];
  int ids[16] = {ia.x, ia.y, ia.z, ia.w, ib.x, ib.y, ib.z, ib.w,
                 ic.x, ic.y, ic.z, ic.w, id4.x, id4.y, id4.z, id4.w};
  int n = 0;
  #pragma unroll
  for (int p = 0; p < 16; ++p) n += (actb[ids[p] << shift] != 0);
  outact[k] = (n >= ACTIVE_THRESHOLD) ? 1.0f : 0.0f;
}

__global__ __launch_bounds__(NTHREADS, 2) void decoder_kernel(
    const float* __restrict__ prev, const int* __restrict__ pidx,
    const float* __restrict__ w, const float* __restrict__ b,
    const float* __restrict__ actf, float* __restrict__ out,
    float* __restrict__ outact) {
  extern __shared__ float xs[];               // [2048][18] padded rows
  const int tid  = threadIdx.x;
  const int pos0 = blockIdx.x * POS_TILE;     // 256 blocks = 1 per CU

  // ---- stage prev[:, pos0:pos0+16] into padded rows ----
  #pragma unroll
  for (int it = 0; it < 16; ++it) {
    int linear = (it << 9) + tid;             // 0..8191 chunk index
    int row = linear >> 2;
    int c   = linear & 3;
    *(f32x4*)(&xs[row * ROW_W + (c << 2)]) =
        *(const f32x4*)(prev + row * NN + pos0 + (c << 2));
  }
  __syncthreads();

  for (int it8 = 0; it8 < K_NODES / NTHREADS; ++it8) {   // 8 iters
    int n = (it8 << 9) + tid;                 // wave = 64 consecutive nodes
    const int4*   ip = (const int4*)(pidx + (n << 4));
    const float4* wp = (const float4*)(w + (n << 4));
    float bk = b[n];
    float g  = actf[n];                       // 0.0 / 1.0

    f32x4 a0 = {bk, bk, bk, bk}, a1 = a0, a2 = a0, a3 = a0;

    #pragma unroll
    for (int bb = 0; bb < 4; ++bb) {          // 4 parents per batch
      int4   iv = ip[bb];
      float4 wv = wp[bb];
      const float* r0 = &xs[iv.x * ROW_W];
      const float* r1 = &xs[iv.y * ROW_W];
      const float* r2 = &xs[iv.z * ROW_W];
      const float* r3 = &xs[iv.w * ROW_W];
      // 16 independent ds_read_b128 (imm offsets 0/16/32/48 off 4 bases)
      f32x4 x00 = *(const f32x4*)(r0);      f32x4 x01 = *(const f32x4*)(r0 + 4);
      f32x4 x02 = *(const f32x4*)(r0 + 8);  f32x4 x03 = *(const f32x4*)(r0 + 12);
      f32x4 x10 = *(const f32x4*)(r1);      f32x4 x11 = *(const f32x4*)(r1 + 4);
      f32x4 x12 = *(const f32x4*)(r1 + 8);  f32x4 x13 = *(const f32x4*)(r1 + 12);
      f32x4 x20 = *(const f32x4*)(r2);      f32x4 x21 = *(const f32x4*)(r2 + 4);
      f32x4 x22 = *(const f32x4*)(r2 + 8);  f32x4 x23 = *(const f32x4*)(r2 + 12);
      f32x4 x30 = *(const f32x4*)(r3);      f32x4 x31 = *(const f32x4*)(r3 + 4);
      f32x4 x32 = *(const f32x4*)(r3 + 8);  f32x4 x33 = *(const f32x4*)(r3 + 12);
      // Nothing crosses this: all 16 loads issue before any FMA -> 16 b128
      // in flight per wave (defeats the compiler's liverange-collapsing).
      __builtin_amdgcn_sched_barrier(0);
      a0 += wv.x * x00;  a1 += wv.x * x01;  a2 += wv.x * x02;  a3 += wv.x * x03;
      a0 += wv.y * x10;  a1 += wv.y * x11;  a2 += wv.y * x12;  a3 += wv.y * x13;
      a0 += wv.z * x20;  a1 += wv.z * x21;  a2 += wv.z * x22;  a3 += wv.z * x23;
      a0 += wv.w * x30;  a1 += wv.w * x31;  a2 += wv.w * x32;  a3 += wv.w * x33;
    }

    f32x4 o0, o1, o2, o3;
    o0.x = fast_tanh(a0.x) * g; o0.y = fast_tanh(a0.y) * g;
    o0.z = fast_tanh(a0.z) * g; o0.w = fast_tanh(a0.w) * g;
    o1.x = fast_tanh(a1.x) * g; o1.y = fast_tanh(a1.y) * g;
    o1.z = fast_tanh(a1.z) * g; o1.w = fast_tanh(a1.w) * g;
    o2.x = fast_tanh(a2.x) * g; o2.y = fast_tanh(a2.y) * g;
    o2.z = fast_tanh(a2.z) * g; o2.w = fast_tanh(a2.w) * g;
    o3.x = fast_tanh(a3.x) * g; o3.y = fast_tanh(a3.y) * g;
    o3.z = fast_tanh(a3.z) * g; o3.w = fast_tanh(a3.w) * g;

    // thread writes its node's full 64B line (contiguous, trivially merged)
    float* op = out + (size_t)n * NN + pos0;
    *(f32x4*)(op)      = o0;
    *(f32x4*)(op + 4)  = o1;
    *(f32x4*)(op + 8)  = o2;
    *(f32x4*)(op + 12) = o3;

    if (blockIdx.x == 0) outact[n] = g;   // block 0 covers all nodes
  }
}

extern "C" void kernel_launch(void* const* d_in, const int* in_sizes, int n_in,
                              void* d_out, int out_size, void* d_ws, size_t ws_size,
                              hipStream_t stream) {
  const float* prev  = (const float*)d_in[0];
  const void*  isact = d_in[1];
  const int*   pidx  = (const int*)d_in[2];
  const float* w     = (const float*)d_in[3];
  const float* b     = (const float*)d_in[4];
  float* out    = (float*)d_out;
  float* outact = out + OUT_ELEMS;

  (void)hipFuncSetAttribute((const void*)decoder_kernel,
                            hipFuncAttributeMaxDynamicSharedMemorySize, LDS_BYTES);

  act_kernel<<<K_NODES / 256, 256, 0, stream>>>(
      pidx, (const unsigned int*)isact, outact);
  decoder_kernel<<<NN / POS_TILE, NTHREADS, LDS_BYTES, stream>>>(
      prev, pidx, w, b, outact, out, outact);
}

// Round 10
// 106.734 us; speedup vs baseline: 1.2434x; 1.2434x over previous
//
#include <hip/hip_runtime.h>

// DecoderLayer: out[k,n,m] = tanh(sum_p w[k,p]*prev[idx[k,p],n,m] + b[k]),
// gated by (#active parents >= 12).  M=2048, K=4096, NN=4096 (64x64), P=16.
//
// R10: coalesced-gather reformulation. Measured law (R2-R9): address-divergent
// LDS gathers serialize to ~16B/cyc/CU (~100us for our 1GB) no matter what;
// bank-conflict counters never see it. So: wave = ONE node x 64 CONTIGUOUS
// positions; each parent read is prev[idx*4096+pos0+lane] = 256B contiguous
// = 4 full lines/instr, from L2 (per-tile slice 512KB; 8 tiles pinned per
// XCD = 4MB = L2). No LDS. Scalar dword loads (1 VGPR each) keep 16 in
// flight (R7's f32x4 loads collapsed to ~3). Coalesced nontemporal stores.

#define M_ROWS   2048
#define K_NODES  4096
#define NN       4096
#define POS_TILE 64
#define NTHREADS 512
#define OUT_ELEMS (K_NODES * NN)
#define ACTIVE_THRESHOLD 12

__device__ __forceinline__ float fast_tanh(float x) {
  float ax = __builtin_fabsf(x);
  float e  = __expf(-2.0f * ax);
  float r  = (1.0f - e) * __builtin_amdgcn_rcpf(1.0f + e);
  return __builtin_copysignf(r, x);
}

// Gate precompute (off hot path). Runtime-detects isact marshaling:
// any 32-bit word >1 in the first 2048 bytes implies packed bytes.
__global__ __launch_bounds__(256) void act_kernel(
    const int* __restrict__ pidx, const unsigned int* __restrict__ isact,
    float* __restrict__ outact) {
  __shared__ int mode_sh;
  if (threadIdx.x == 0) mode_sh = 0;
  __syncthreads();
  int bad = 0;
  for (int i = threadIdx.x; i < 512; i += 256) bad |= (isact[i] > 1u);
  if (bad) atomicOr(&mode_sh, 1);
  __syncthreads();
  const int shift = mode_sh ? 0 : 2;   // LSB byte of a 0/1 int32 == its value
  const unsigned char* actb = (const unsigned char*)isact;

  int k = blockIdx.x * 256 + threadIdx.x;
  const int4* ip = (const int4*)(pidx + k * 16);
  int4 ia = ip[0], ib = ip[1], ic = ip[2], id4 = ip[3];
  int ids[16] = {ia.x, ia.y, ia.z, ia.w, ib.x, ib.y, ib.z, ib.w,
                 ic.x, ic.y, ic.z, ic.w, id4.x, id4.y, id4.z, id4.w};
  int n = 0;
  #pragma unroll
  for (int p = 0; p < 16; ++p) n += (actb[ids[p] << shift] != 0);
  outact[k] = (n >= ACTIVE_THRESHOLD) ? 1.0f : 0.0f;
}

__global__ __launch_bounds__(NTHREADS, 4) void decoder_kernel(
    const float* __restrict__ prev, const int* __restrict__ pidx,
    const float* __restrict__ w, const float* __restrict__ b,
    const float* __restrict__ actf, float* __restrict__ out,
    float* __restrict__ outact) {
  const int tid  = threadIdx.x;
  const int lane = tid & 63;
  const int wv   = tid >> 6;               // wave id in block, 0..7
  const int bid  = blockIdx.x;             // 0..1023

  // XCD pinning: bid%8 = XCD (dispatch round-robin). Each XCD owns 8 tiles;
  // the 16 sub-blocks of a tile land on the same XCD -> slice set 8x512KB=L2.
  const int xcd  = bid & 7;
  const int j    = bid >> 3;               // 0..127
  const int tile = xcd * 8 + (j >> 4);     // 0..63
  const int sub  = j & 15;                 // 0..15
  const int pos0 = tile * POS_TILE;
  const int n0   = sub * 256;              // block covers 256 nodes

  const float* __restrict__ pb = prev + pos0 + lane;

  #pragma unroll 2
  for (int it = 0; it < 32; ++it) {        // wave: 32 nodes, one per iter
    int n = n0 + (it << 3) + wv;
    const int4*   ip = (const int4*)(pidx + (n << 4));
    const float4* wp = (const float4*)(w + (n << 4));
    int4   i0 = ip[0], i1 = ip[1], i2 = ip[2], i3 = ip[3];
    float4 w0 = wp[0], w1 = wp[1], w2 = wp[2], w3 = wp[3];
    float  bk = b[n];
    float  g  = actf[n];                   // 0.0 / 1.0

    // 16 independent coalesced dword loads (4 lines each), 1 VGPR apiece.
    float x0  = pb[(size_t)i0.x << 12];
    float x1  = pb[(size_t)i0.y << 12];
    float x2  = pb[(size_t)i0.z << 12];
    float x3  = pb[(size_t)i0.w << 12];
    float x4  = pb[(size_t)i1.x << 12];
    float x5  = pb[(size_t)i1.y << 12];
    float x6  = pb[(size_t)i1.z << 12];
    float x7  = pb[(size_t)i1.w << 12];
    float x8  = pb[(size_t)i2.x << 12];
    float x9  = pb[(size_t)i2.y << 12];
    float x10 = pb[(size_t)i2.z << 12];
    float x11 = pb[(size_t)i2.w << 12];
    float x12 = pb[(size_t)i3.x << 12];
    float x13 = pb[(size_t)i3.y << 12];
    float x14 = pb[(size_t)i3.z << 12];
    float x15 = pb[(size_t)i3.w << 12];

    // two chains, consuming in issue order (vmcnt waits stay incremental)
    float a0 = bk + w0.x * x0;
    float a1 =      w0.y * x1;
    a0 += w0.z * x2;   a1 += w0.w * x3;
    a0 += w1.x * x4;   a1 += w1.y * x5;
    a0 += w1.z * x6;   a1 += w1.w * x7;
    a0 += w2.x * x8;   a1 += w2.y * x9;
    a0 += w2.z * x10;  a1 += w2.w * x11;
    a0 += w3.x * x12;  a1 += w3.y * x13;
    a0 += w3.z * x14;  a1 += w3.w * x15;

    float o = fast_tanh(a0 + a1) * g;
    __builtin_nontemporal_store(o, out + ((size_t)n << 12) + pos0 + lane);

    if (tile == 0 && lane == 0) outact[n] = g;
  }
}

extern "C" void kernel_launch(void* const* d_in, const int* in_sizes, int n_in,
                              void* d_out, int out_size, void* d_ws, size_t ws_size,
                              hipStream_t stream) {
  const float* prev  = (const float*)d_in[0];
  const void*  isact = d_in[1];
  const int*   pidx  = (const int*)d_in[2];
  const float* w     = (const float*)d_in[3];
  const float* b     = (const float*)d_in[4];
  float* out    = (float*)d_out;
  float* outact = out + OUT_ELEMS;

  act_kernel<<<K_NODES / 256, 256, 0, stream>>>(
      pidx, (const unsigned int*)isact, outact);
  decoder_kernel<<<(NN / POS_TILE) * 16, NTHREADS, 0, stream>>>(
      prev, pidx, w, b, outact, out, outact);
}

// Round 11
// 40.559 us; speedup vs baseline: 3.2720x; 2.6316x over previous
//
#include <hip/hip_runtime.h>

// DecoderLayer: out[k,n,m] = tanh(sum_p w[k,p]*prev[idx[k,p],n,m] + b[k]),
// gated by (#active parents >= 12).  M=2048, K=4096, NN=4096 (64x64), P=16.
//
// R11: measured law (R2-R10): gather cost ~ distinct 128B rows per 16-lane
// quarter-wave; 1GB f32 gather = ~100us any way you slice it. Attack bytes
// and geometry together: bf16(RNE) LDS tile, POS_TILE=32, rows padded to
// 80B (16B-aligned b128, bank-phase cycling - kills R6's 64B-stride clash),
// lane-QUAD per node (4 rows/quarter). Gather instrs 4096->2048/CU at
// ~22cyc -> ~19us pipe demand. Grid=256: 128 tiles x 2 node-halves,
// halves co-located per XCD (16 tiles x 256KB = 4MB = one L2).

#define M_ROWS   2048
#define K_NODES  4096
#define NN       4096
#define POS_TILE 32
#define NTHREADS 512
#define ROW_B    80                          // bytes per padded bf16 row
#define LDS_BYTES (M_ROWS * ROW_B)           // 163840 = 160 KiB (full LDS)
#define OUT_ELEMS (K_NODES * NN)
#define ACTIVE_THRESHOLD 12

typedef float f32x4 __attribute__((ext_vector_type(4)));
typedef unsigned short u16x8 __attribute__((ext_vector_type(8)));

__device__ __forceinline__ float fast_tanh(float x) {
  float ax = __builtin_fabsf(x);
  float e  = __expf(-2.0f * ax);
  float r  = (1.0f - e) * __builtin_amdgcn_rcpf(1.0f + e);
  return __builtin_copysignf(r, x);
}

__device__ __forceinline__ unsigned short f2bf_rne(float f) {
  unsigned u = __float_as_uint(f);
  u += 0x7FFFu + ((u >> 16) & 1u);           // round-to-nearest-even
  return (unsigned short)(u >> 16);
}

// Gate precompute (off hot path). Runtime-detects isact marshaling:
// any 32-bit word >1 in the first 2048 bytes implies packed bytes.
__global__ __launch_bounds__(256) void act_kernel(
    const int* __restrict__ pidx, const unsigned int* __restrict__ isact,
    float* __restrict__ outact) {
  __shared__ int mode_sh;
  if (threadIdx.x == 0) mode_sh = 0;
  __syncthreads();
  int bad = 0;
  for (int i = threadIdx.x; i < 512; i += 256) bad |= (isact[i] > 1u);
  if (bad) atomicOr(&mode_sh, 1);
  __syncthreads();
  const int shift = mode_sh ? 0 : 2;   // LSB byte of a 0/1 int32 == its value
  const unsigned char* actb = (const unsigned char*)isact;

  int k = blockIdx.x * 256 + threadIdx.x;
  const int4* ip = (const int4*)(pidx + k * 16);
  int4 ia = ip[0], ib = ip[1], ic = ip[2], id4 = ip[3];
  int ids[16] = {ia.x, ia.y, ia.z, ia.w, ib.x, ib.y, ib.z, ib.w,
                 ic.x, ic.y, ic.z, ic.w, id4.x, id4.y, id4.z, id4.w};
  int n = 0;
  #pragma unroll
  for (int p = 0; p < 16; ++p) n += (actb[ids[p] << shift] != 0);
  outact[k] = (n >= ACTIVE_THRESHOLD) ? 1.0f : 0.0f;
}

// unpack-and-FMA one parent: 8 bf16 positions, scalar f32 accs
#define PFMA(vv, wv)                                              \
  { float wv_ = (wv);                                             \
    a0 += wv_ * __uint_as_float((unsigned)(vv)[0] << 16);         \
    a1 += wv_ * __uint_as_float((unsigned)(vv)[1] << 16);         \
    a2 += wv_ * __uint_as_float((unsigned)(vv)[2] << 16);         \
    a3 += wv_ * __uint_as_float((unsigned)(vv)[3] << 16);         \
    a4 += wv_ * __uint_as_float((unsigned)(vv)[4] << 16);         \
    a5 += wv_ * __uint_as_float((unsigned)(vv)[5] << 16);         \
    a6 += wv_ * __uint_as_float((unsigned)(vv)[6] << 16);         \
    a7 += wv_ * __uint_as_float((unsigned)(vv)[7] << 16); }

__global__ __launch_bounds__(NTHREADS, 2) void decoder_kernel(
    const float* __restrict__ prev, const int* __restrict__ pidx,
    const float* __restrict__ w, const float* __restrict__ b,
    const float* __restrict__ actf, float* __restrict__ out,
    float* __restrict__ outact) {
  extern __shared__ char xb[];               // [2048 rows][80 B] bf16 tile
  const int tid = threadIdx.x;
  const int bid = blockIdx.x;                // 0..255

  // XCD co-location: xcd = bid&7; each XCD owns 16 tiles; the two node-half
  // blocks of a tile land on the same XCD (slice set = 4MB = its L2).
  const int xcd   = bid & 7;
  const int loc   = bid >> 3;                // 0..31
  const int tile  = xcd * 16 + (loc >> 1);   // 0..127
  const int half  = loc & 1;
  const int pos0  = tile * POS_TILE;
  const int nbase = half * (K_NODES / 2);

  // ---- stage prev[:, pos0:pos0+32] as bf16-RNE, 80B padded rows ----
  #pragma unroll
  for (int it = 0; it < 16; ++it) {
    int ci = (it << 9) + tid;                // chunk index 0..8191 (= r*4+c)
    int r = ci >> 2, c = ci & 3;
    const float* sp = prev + r * NN + pos0 + (c << 3);
    f32x4 v0 = *(const f32x4*)sp;
    f32x4 v1 = *(const f32x4*)(sp + 4);
    u16x8 o;
    o[0] = f2bf_rne(v0.x); o[1] = f2bf_rne(v0.y);
    o[2] = f2bf_rne(v0.z); o[3] = f2bf_rne(v0.w);
    o[4] = f2bf_rne(v1.x); o[5] = f2bf_rne(v1.y);
    o[6] = f2bf_rne(v1.z); o[7] = f2bf_rne(v1.w);
    *(u16x8*)(xb + r * ROW_B + (c << 4)) = o;
  }
  __syncthreads();

  const int q = tid & 3;                     // 16B chunk = 8 positions
  const int s = tid >> 2;                    // node slot 0..127
  const int coff = q << 4;                   // byte offset within row

  for (int it = 0; it < 16; ++it) {
    int n = nbase + (it << 7) + s;
    const int4*   ip = (const int4*)(pidx + (n << 4));
    const float4* wp = (const float4*)(w + (n << 4));
    int4   i0 = ip[0], i1 = ip[1], i2 = ip[2], i3 = ip[3];
    float4 w0 = wp[0], w1 = wp[1], w2 = wp[2], w3 = wp[3];
    float  bk = b[n];
    float  g  = actf[n];                     // 0.0 / 1.0

    float a0 = bk, a1 = bk, a2 = bk, a3 = bk;
    float a4 = bk, a5 = bk, a6 = bk, a7 = bk;

    // batch 1: parents 0..7 — 8 independent ds_read_b128
    u16x8 v0 = *(const u16x8*)(xb + i0.x * ROW_B + coff);
    u16x8 v1 = *(const u16x8*)(xb + i0.y * ROW_B + coff);
    u16x8 v2 = *(const u16x8*)(xb + i0.z * ROW_B + coff);
    u16x8 v3 = *(const u16x8*)(xb + i0.w * ROW_B + coff);
    u16x8 v4 = *(const u16x8*)(xb + i1.x * ROW_B + coff);
    u16x8 v5 = *(const u16x8*)(xb + i1.y * ROW_B + coff);
    u16x8 v6 = *(const u16x8*)(xb + i1.z * ROW_B + coff);
    u16x8 v7 = *(const u16x8*)(xb + i1.w * ROW_B + coff);
    __builtin_amdgcn_sched_barrier(0);       // keep 8 reads in flight
    PFMA(v0, w0.x) PFMA(v1, w0.y) PFMA(v2, w0.z) PFMA(v3, w0.w)
    PFMA(v4, w1.x) PFMA(v5, w1.y) PFMA(v6, w1.z) PFMA(v7, w1.w)

    // batch 2: parents 8..15
    v0 = *(const u16x8*)(xb + i2.x * ROW_B + coff);
    v1 = *(const u16x8*)(xb + i2.y * ROW_B + coff);
    v2 = *(const u16x8*)(xb + i2.z * ROW_B + coff);
    v3 = *(const u16x8*)(xb + i2.w * ROW_B + coff);
    v4 = *(const u16x8*)(xb + i3.x * ROW_B + coff);
    v5 = *(const u16x8*)(xb + i3.y * ROW_B + coff);
    v6 = *(const u16x8*)(xb + i3.z * ROW_B + coff);
    v7 = *(const u16x8*)(xb + i3.w * ROW_B + coff);
    __builtin_amdgcn_sched_barrier(0);
    PFMA(v0, w2.x) PFMA(v1, w2.y) PFMA(v2, w2.z) PFMA(v3, w2.w)
    PFMA(v4, w3.x) PFMA(v5, w3.y) PFMA(v6, w3.z) PFMA(v7, w3.w)

    f32x4 o0, o1;
    o0.x = fast_tanh(a0) * g; o0.y = fast_tanh(a1) * g;
    o0.z = fast_tanh(a2) * g; o0.w = fast_tanh(a3) * g;
    o1.x = fast_tanh(a4) * g; o1.y = fast_tanh(a5) * g;
    o1.z = fast_tanh(a6) * g; o1.w = fast_tanh(a7) * g;

    // quad writes 128B contiguous of out row n
    float* op = out + ((size_t)n << 12) + pos0 + (q << 3);
    *(f32x4*)op       = o0;
    *(f32x4*)(op + 4) = o1;

    if (tile == 0 && q == 0) outact[n] = g;  // bid 0 & 8 cover all n
  }
}

extern "C" void kernel_launch(void* const* d_in, const int* in_sizes, int n_in,
                              void* d_out, int out_size, void* d_ws, size_t ws_size,
                              hipStream_t stream) {
  const float* prev  = (const float*)d_in[0];
  const void*  isact = d_in[1];
  const int*   pidx  = (const int*)d_in[2];
  const float* w     = (const float*)d_in[3];
  const float* b     = (const float*)d_in[4];
  float* out    = (float*)d_out;
  float* outact = out + OUT_ELEMS;

  (void)hipFuncSetAttribute((const void*)decoder_kernel,
                            hipFuncAttributeMaxDynamicSharedMemorySize, LDS_BYTES);

  act_kernel<<<K_NODES / 256, 256, 0, stream>>>(
      pidx, (const unsigned int*)isact, outact);
  decoder_kernel<<<(NN / POS_TILE) * 2, NTHREADS, LDS_BYTES, stream>>>(
      prev, pidx, w, b, outact, out, outact);
}

// Round 12
// 38.823 us; speedup vs baseline: 3.4183x; 1.0447x over previous
//
#include <hip/hip_runtime.h>

// DecoderLayer: out[k,n,m] = tanh(sum_p w[k,p]*prev[idx[k,p],n,m] + b[k]),
// gated by (#active parents >= 12).  M=2048, K=4096, NN=4096 (64x64), P=16.
//
// R12 = R11 (bf16 LDS tile, 80B padded rows, lane-quad per node) with
// 1024-thread blocks: same 160KiB tile, 1 block/CU, but 4 waves/SIMD
// instead of 2 -> 2x latency coverage on LDS queue + VALU interleave.
// R11 measured: conflicts 3.3M (~6cyc/instr), VALUBusy 36%, occ 16%,
// dur 44us vs ~21us overlapped floor -> pure latency starvation.

#define M_ROWS   2048
#define K_NODES  4096
#define NN       4096
#define POS_TILE 32
#define NTHREADS 1024
#define ROW_B    80                          // bytes per padded bf16 row
#define LDS_BYTES (M_ROWS * ROW_B)           // 163840 = 160 KiB (full LDS)
#define OUT_ELEMS (K_NODES * NN)
#define ACTIVE_THRESHOLD 12

typedef float f32x4 __attribute__((ext_vector_type(4)));
typedef unsigned short u16x8 __attribute__((ext_vector_type(8)));

__device__ __forceinline__ float fast_tanh(float x) {
  float ax = __builtin_fabsf(x);
  float e  = __expf(-2.0f * ax);
  float r  = (1.0f - e) * __builtin_amdgcn_rcpf(1.0f + e);
  return __builtin_copysignf(r, x);
}

__device__ __forceinline__ unsigned short f2bf_rne(float f) {
  unsigned u = __float_as_uint(f);
  u += 0x7FFFu + ((u >> 16) & 1u);           // round-to-nearest-even
  return (unsigned short)(u >> 16);
}

// Gate precompute (off hot path). Runtime-detects isact marshaling:
// any 32-bit word >1 in the first 2048 bytes implies packed bytes.
__global__ __launch_bounds__(256) void act_kernel(
    const int* __restrict__ pidx, const unsigned int* __restrict__ isact,
    float* __restrict__ outact) {
  __shared__ int mode_sh;
  if (threadIdx.x == 0) mode_sh = 0;
  __syncthreads();
  int bad = 0;
  for (int i = threadIdx.x; i < 512; i += 256) bad |= (isact[i] > 1u);
  if (bad) atomicOr(&mode_sh, 1);
  __syncthreads();
  const int shift = mode_sh ? 0 : 2;   // LSB byte of a 0/1 int32 == its value
  const unsigned char* actb = (const unsigned char*)isact;

  int k = blockIdx.x * 256 + threadIdx.x;
  const int4* ip = (const int4*)(pidx + k * 16);
  int4 ia = ip[0], ib = ip[1], ic = ip[2], id4 = ip[3];
  int ids[16] = {ia.x, ia.y, ia.z, ia.w, ib.x, ib.y, ib.z, ib.w,
                 ic.x, ic.y, ic.z, ic.w, id4.x, id4.y, id4.z, id4.w};
  int n = 0;
  #pragma unroll
  for (int p = 0; p < 16; ++p) n += (actb[ids[p] << shift] != 0);
  outact[k] = (n >= ACTIVE_THRESHOLD) ? 1.0f : 0.0f;
}

// unpack-and-FMA one parent: 8 bf16 positions, scalar f32 accs
#define PFMA(vv, wv)                                              \
  { float wv_ = (wv);                                             \
    a0 += wv_ * __uint_as_float((unsigned)(vv)[0] << 16);         \
    a1 += wv_ * __uint_as_float((unsigned)(vv)[1] << 16);         \
    a2 += wv_ * __uint_as_float((unsigned)(vv)[2] << 16);         \
    a3 += wv_ * __uint_as_float((unsigned)(vv)[3] << 16);         \
    a4 += wv_ * __uint_as_float((unsigned)(vv)[4] << 16);         \
    a5 += wv_ * __uint_as_float((unsigned)(vv)[5] << 16);         \
    a6 += wv_ * __uint_as_float((unsigned)(vv)[6] << 16);         \
    a7 += wv_ * __uint_as_float((unsigned)(vv)[7] << 16); }

__global__ __launch_bounds__(NTHREADS, 1) void decoder_kernel(
    const float* __restrict__ prev, const int* __restrict__ pidx,
    const float* __restrict__ w, const float* __restrict__ b,
    const float* __restrict__ actf, float* __restrict__ out,
    float* __restrict__ outact) {
  extern __shared__ char xb[];               // [2048 rows][80 B] bf16 tile
  const int tid = threadIdx.x;
  const int bid = blockIdx.x;                // 0..255

  // XCD co-location: xcd = bid&7; each XCD owns 16 tiles; the two node-half
  // blocks of a tile land on the same XCD (slice set = 4MB = its L2).
  const int xcd   = bid & 7;
  const int loc   = bid >> 3;                // 0..31
  const int tile  = xcd * 16 + (loc >> 1);   // 0..127
  const int half  = loc & 1;
  const int pos0  = tile * POS_TILE;
  const int nbase = half * (K_NODES / 2);

  // ---- stage prev[:, pos0:pos0+32] as bf16-RNE, 80B padded rows ----
  #pragma unroll
  for (int it = 0; it < 8; ++it) {
    int ci = (it << 10) + tid;               // chunk index 0..8191 (= r*4+c)
    int r = ci >> 2, c = ci & 3;
    const float* sp = prev + r * NN + pos0 + (c << 3);
    f32x4 v0 = *(const f32x4*)sp;
    f32x4 v1 = *(const f32x4*)(sp + 4);
    u16x8 o;
    o[0] = f2bf_rne(v0.x); o[1] = f2bf_rne(v0.y);
    o[2] = f2bf_rne(v0.z); o[3] = f2bf_rne(v0.w);
    o[4] = f2bf_rne(v1.x); o[5] = f2bf_rne(v1.y);
    o[6] = f2bf_rne(v1.z); o[7] = f2bf_rne(v1.w);
    *(u16x8*)(xb + r * ROW_B + (c << 4)) = o;
  }
  __syncthreads();

  const int q = tid & 3;                     // 16B chunk = 8 positions
  const int s = tid >> 2;                    // node slot 0..255
  const int coff = q << 4;                   // byte offset within row

  for (int it = 0; it < 8; ++it) {
    int n = nbase + (it << 8) + s;
    const int4*   ip = (const int4*)(pidx + (n << 4));
    const float4* wp = (const float4*)(w + (n << 4));
    int4   i0 = ip[0], i1 = ip[1], i2 = ip[2], i3 = ip[3];
    float4 w0 = wp[0], w1 = wp[1], w2 = wp[2], w3 = wp[3];
    float  bk = b[n];
    float  g  = actf[n];                     // 0.0 / 1.0

    float a0 = bk, a1 = bk, a2 = bk, a3 = bk;
    float a4 = bk, a5 = bk, a6 = bk, a7 = bk;

    // batch 1: parents 0..7 — 8 independent ds_read_b128
    u16x8 v0 = *(const u16x8*)(xb + i0.x * ROW_B + coff);
    u16x8 v1 = *(const u16x8*)(xb + i0.y * ROW_B + coff);
    u16x8 v2 = *(const u16x8*)(xb + i0.z * ROW_B + coff);
    u16x8 v3 = *(const u16x8*)(xb + i0.w * ROW_B + coff);
    u16x8 v4 = *(const u16x8*)(xb + i1.x * ROW_B + coff);
    u16x8 v5 = *(const u16x8*)(xb + i1.y * ROW_B + coff);
    u16x8 v6 = *(const u16x8*)(xb + i1.z * ROW_B + coff);
    u16x8 v7 = *(const u16x8*)(xb + i1.w * ROW_B + coff);
    __builtin_amdgcn_sched_barrier(0);       // keep 8 reads in flight
    PFMA(v0, w0.x) PFMA(v1, w0.y) PFMA(v2, w0.z) PFMA(v3, w0.w)
    PFMA(v4, w1.x) PFMA(v5, w1.y) PFMA(v6, w1.z) PFMA(v7, w1.w)

    // batch 2: parents 8..15
    v0 = *(const u16x8*)(xb + i2.x * ROW_B + coff);
    v1 = *(const u16x8*)(xb + i2.y * ROW_B + coff);
    v2 = *(const u16x8*)(xb + i2.z * ROW_B + coff);
    v3 = *(const u16x8*)(xb + i2.w * ROW_B + coff);
    v4 = *(const u16x8*)(xb + i3.x * ROW_B + coff);
    v5 = *(const u16x8*)(xb + i3.y * ROW_B + coff);
    v6 = *(const u16x8*)(xb + i3.z * ROW_B + coff);
    v7 = *(const u16x8*)(xb + i3.w * ROW_B + coff);
    __builtin_amdgcn_sched_barrier(0);
    PFMA(v0, w2.x) PFMA(v1, w2.y) PFMA(v2, w2.z) PFMA(v3, w2.w)
    PFMA(v4, w3.x) PFMA(v5, w3.y) PFMA(v6, w3.z) PFMA(v7, w3.w)

    f32x4 o0, o1;
    o0.x = fast_tanh(a0) * g; o0.y = fast_tanh(a1) * g;
    o0.z = fast_tanh(a2) * g; o0.w = fast_tanh(a3) * g;
    o1.x = fast_tanh(a4) * g; o1.y = fast_tanh(a5) * g;
    o1.z = fast_tanh(a6) * g; o1.w = fast_tanh(a7) * g;

    // quad writes 128B contiguous of out row n
    float* op = out + ((size_t)n << 12) + pos0 + (q << 3);
    *(f32x4*)op       = o0;
    *(f32x4*)(op + 4) = o1;

    if (tile == 0 && q == 0) outact[n] = g;  // bid 0 & 8 cover all n
  }
}

extern "C" void kernel_launch(void* const* d_in, const int* in_sizes, int n_in,
                              void* d_out, int out_size, void* d_ws, size_t ws_size,
                              hipStream_t stream) {
  const float* prev  = (const float*)d_in[0];
  const void*  isact = d_in[1];
  const int*   pidx  = (const int*)d_in[2];
  const float* w     = (const float*)d_in[3];
  const float* b     = (const float*)d_in[4];
  float* out    = (float*)d_out;
  float* outact = out + OUT_ELEMS;

  (void)hipFuncSetAttribute((const void*)decoder_kernel,
                            hipFuncAttributeMaxDynamicSharedMemorySize, LDS_BYTES);

  act_kernel<<<K_NODES / 256, 256, 0, stream>>>(
      pidx, (const unsigned int*)isact, outact);
  decoder_kernel<<<(NN / POS_TILE) * 2, NTHREADS, LDS_BYTES, stream>>>(
      prev, pidx, w, b, outact, out, outact);
}